// Round 1
// baseline (5185.950 us; speedup 1.0000x reference)
//
#include <hip/hip_runtime.h>
#include <hip/hip_bf16.h>
#include <math.h>

#define N_NODES 50000
#define N_EDGES 800000
#define HEADS 4
#define NEG 0.2f

// ---------- ordered-float encoding for atomicMax on f32 ----------
// key order == float order; key 0x00000000 decodes to -NaN (below everything),
// so hipMemsetAsync(0) is a valid "-inf" init.
__device__ __forceinline__ unsigned f2ord(float x) {
    unsigned u = __float_as_uint(x);
    return (u & 0x80000000u) ? ~u : (u | 0x80000000u);
}
__device__ __forceinline__ float ord2f(unsigned k) {
    unsigned u = (k & 0x80000000u) ? (k & 0x7FFFFFFFu) : ~k;
    return __uint_as_float(u);
}

// ---------- GEMM: out[N, FOUT] = h[N, FIN] @ W[FIN, FOUT] ----------
// block = 128 threads, 16 rows per block; h tile staged in LDS; W via L1/L2.
template<int FIN, int FOUT>
__global__ __launch_bounds__(128) void gemm_kernel(const float* __restrict__ h,
                                                   const float* __restrict__ W,
                                                   float* __restrict__ out) {
    constexpr int ROWS = 16;
    constexpr int SUBS = 128 / FOUT;   // thread row-subgroups (1 or 4)
    constexpr int RPT  = ROWS / SUBS;  // rows per thread (16 or 4)
    __shared__ float hs[ROWS][FIN];
    const int tid = threadIdx.x;
    const int rbase = blockIdx.x * ROWS;
    for (int i = tid; i < ROWS * FIN; i += 128) {
        int r = i / FIN, c = i % FIN;
        int gr = rbase + r;
        hs[r][c] = (gr < N_NODES) ? h[(size_t)gr * FIN + c] : 0.f;
    }
    __syncthreads();
    const int col = tid % FOUT;
    const int sub = tid / FOUT;
    float acc[RPT];
#pragma unroll
    for (int i = 0; i < RPT; ++i) acc[i] = 0.f;
    for (int k = 0; k < FIN; ++k) {
        float w = W[k * FOUT + col];
#pragma unroll
        for (int i = 0; i < RPT; ++i) acc[i] += hs[sub * RPT + i][k] * w;
    }
#pragma unroll
    for (int i = 0; i < RPT; ++i) {
        int gr = rbase + sub * RPT + i;
        if (gr < N_NODES) out[(size_t)gr * FOUT + col] = acc[i];
    }
}

// ---------- edge score: e[E,H] = sum_d lrelu(el+er)*attn ; atomicMax m ----------
template<int D>
__global__ __launch_bounds__(256) void edge_score(const float* __restrict__ feat,
                                                  const int* __restrict__ src,
                                                  const int* __restrict__ dst,
                                                  const float* __restrict__ attn,
                                                  float* __restrict__ e,
                                                  unsigned* __restrict__ m) {
    constexpr int F   = HEADS * D;   // floats per feat row (128 or 32)
    constexpr int LPE = F / 4;       // lanes per edge (32 or 8)
    constexpr int EPW = 64 / LPE;    // edges per wave (2 or 8)
    const int lane = threadIdx.x & 63;
    const int wave = (blockIdx.x * blockDim.x + threadIdx.x) >> 6;
    const int nwaves = (gridDim.x * blockDim.x) >> 6;
    const int sub  = lane / LPE;
    const int l    = lane % LPE;
    const int head = (l * 4) / D;
    const int dpos = (l * 4) % D;
    const float4 a4 = *(const float4*)(attn + head * D + dpos);
    for (int eb = wave * EPW; eb < N_EDGES; eb += nwaves * EPW) {
        const int eidx = eb + sub;                       // E % EPW == 0 -> in range
        const int sidx = src[eidx], didx = dst[eidx];
        const float4 el4 = *(const float4*)(feat + (size_t)sidx * F + l * 4);
        const float4 er4 = *(const float4*)(feat + (size_t)didx * F + l * 4);
        float vx, sum = 0.f;
        vx = el4.x + er4.x; vx = vx > 0.f ? vx : vx * NEG; sum += vx * a4.x;
        vx = el4.y + er4.y; vx = vx > 0.f ? vx : vx * NEG; sum += vx * a4.y;
        vx = el4.z + er4.z; vx = vx > 0.f ? vx : vx * NEG; sum += vx * a4.z;
        vx = el4.w + er4.w; vx = vx > 0.f ? vx : vx * NEG; sum += vx * a4.w;
#pragma unroll
        for (int off = 1; off < D / 4; off <<= 1)
            sum += __shfl_xor(sum, off, 64);
        if (dpos == 0) {
            e[(size_t)eidx * HEADS + head] = sum;
            atomicMax(&m[(size_t)didx * HEADS + head], f2ord(sum));
        }
    }
}

// ---------- exp + segment sum: ex = exp(e - m[dst]); s += ex ----------
__global__ __launch_bounds__(256) void edge_exp(float* __restrict__ e,
                                                const int* __restrict__ dst,
                                                const unsigned* __restrict__ m,
                                                float* __restrict__ s) {
    const int stride = gridDim.x * blockDim.x;
    for (int i = blockIdx.x * blockDim.x + threadIdx.x; i < N_EDGES * HEADS; i += stride) {
        const int eidx = i >> 2, h = i & 3;
        const int d = dst[eidx];
        const float mv = ord2f(m[d * HEADS + h]);
        const float ex = expf(e[i] - mv);
        e[i] = ex;
        atomicAdd(&s[d * HEADS + h], ex);
    }
}

// ---------- aggregate: rst[dst] += feat[src] * ex/s[dst] ----------
template<int D>
__global__ __launch_bounds__(256) void edge_aggr(const float* __restrict__ feat,
                                                 const int* __restrict__ src,
                                                 const int* __restrict__ dst,
                                                 const float* __restrict__ ex,
                                                 const float* __restrict__ s,
                                                 float* __restrict__ rst) {
    constexpr int F   = HEADS * D;
    constexpr int LPE = F / 4;
    constexpr int EPW = 64 / LPE;
    const int lane = threadIdx.x & 63;
    const int wave = (blockIdx.x * blockDim.x + threadIdx.x) >> 6;
    const int nwaves = (gridDim.x * blockDim.x) >> 6;
    const int sub  = lane / LPE;
    const int l    = lane % LPE;
    const int head = (l * 4) / D;
    for (int eb = wave * EPW; eb < N_EDGES; eb += nwaves * EPW) {
        const int eidx = eb + sub;
        const int sidx = src[eidx], didx = dst[eidx];
        const float a = ex[(size_t)eidx * HEADS + head] / s[didx * HEADS + head];
        const float4 el4 = *(const float4*)(feat + (size_t)sidx * F + l * 4);
        float* r = rst + (size_t)didx * F + l * 4;
        atomicAdd(r + 0, el4.x * a);
        atomicAdd(r + 1, el4.y * a);
        atomicAdd(r + 2, el4.z * a);
        atomicAdd(r + 3, el4.w * a);
    }
}

// ---------- elementwise ELU in place ----------
__global__ __launch_bounds__(256) void elu_kernel(float* __restrict__ x, int n) {
    const int stride = gridDim.x * blockDim.x;
    for (int i = blockIdx.x * blockDim.x + threadIdx.x; i < n; i += stride) {
        float v = x[i];
        x[i] = v > 0.f ? v : expm1f(v);
    }
}

// ---------- final head-mean: out[n,d] = mean_h rst[n,h,d], D=8 ----------
__global__ __launch_bounds__(256) void mean_kernel(const float* __restrict__ rst,
                                                   float* __restrict__ out) {
    const int stride = gridDim.x * blockDim.x;
    for (int i = blockIdx.x * blockDim.x + threadIdx.x; i < N_NODES * 8; i += stride) {
        const int n = i >> 3, d = i & 7;
        const float* r = rst + (size_t)n * 32 + d;
        out[i] = 0.25f * (r[0] + r[8] + r[16] + r[24]);
    }
}

extern "C" void kernel_launch(void* const* d_in, const int* in_sizes, int n_in,
                              void* d_out, int out_size, void* d_ws, size_t ws_size,
                              hipStream_t stream) {
    const float* features = (const float*)d_in[0];
    const float* W0 = (const float*)d_in[1];  const float* attn0 = (const float*)d_in[2];
    const float* W1 = (const float*)d_in[3];  const float* attn1 = (const float*)d_in[4];
    const float* W2 = (const float*)d_in[5];  const float* attn2 = (const float*)d_in[6];
    const float* W3 = (const float*)d_in[7];  const float* attn3 = (const float*)d_in[8];
    const int* src = (const int*)d_in[9];
    const int* dst = (const int*)d_in[10];
    float* out = (float*)d_out;

    // workspace layout (floats)
    float* bufA = (float*)d_ws;                 // N*128  h / rst
    float* feat = bufA + (size_t)N_NODES * 128; // N*128  projected feats
    float* e    = feat + (size_t)N_NODES * 128; // E*4    scores -> ex
    unsigned* m = (unsigned*)(e + (size_t)N_EDGES * HEADS); // N*4 ordered-max keys
    float* s    = (float*)(m + (size_t)N_NODES * HEADS);    // N*4 softmax denom

    const int EB = 2048, ET = 256;   // edge-kernel launch shape
    const int GB = (N_NODES + 15) / 16;

    // ---------------- layer 0 (FIN=16 -> D=32) ----------------
    gemm_kernel<16, 128><<<GB, 128, 0, stream>>>(features, W0, feat);
    hipMemsetAsync(m, 0, (size_t)N_NODES * HEADS * 2 * 4, stream);  // m and s
    hipMemsetAsync(bufA, 0, (size_t)N_NODES * 128 * 4, stream);
    edge_score<32><<<EB, ET, 0, stream>>>(feat, src, dst, attn0, e, m);
    edge_exp<<<EB, ET, 0, stream>>>(e, dst, m, s);
    edge_aggr<32><<<EB, ET, 0, stream>>>(feat, src, dst, e, s, bufA);
    elu_kernel<<<EB, ET, 0, stream>>>(bufA, N_NODES * 128);

    // ---------------- layer 1 ----------------
    gemm_kernel<128, 128><<<GB, 128, 0, stream>>>(bufA, W1, feat);
    hipMemsetAsync(m, 0, (size_t)N_NODES * HEADS * 2 * 4, stream);
    hipMemsetAsync(bufA, 0, (size_t)N_NODES * 128 * 4, stream);
    edge_score<32><<<EB, ET, 0, stream>>>(feat, src, dst, attn1, e, m);
    edge_exp<<<EB, ET, 0, stream>>>(e, dst, m, s);
    edge_aggr<32><<<EB, ET, 0, stream>>>(feat, src, dst, e, s, bufA);
    elu_kernel<<<EB, ET, 0, stream>>>(bufA, N_NODES * 128);

    // ---------------- layer 2 ----------------
    gemm_kernel<128, 128><<<GB, 128, 0, stream>>>(bufA, W2, feat);
    hipMemsetAsync(m, 0, (size_t)N_NODES * HEADS * 2 * 4, stream);
    hipMemsetAsync(bufA, 0, (size_t)N_NODES * 128 * 4, stream);
    edge_score<32><<<EB, ET, 0, stream>>>(feat, src, dst, attn2, e, m);
    edge_exp<<<EB, ET, 0, stream>>>(e, dst, m, s);
    edge_aggr<32><<<EB, ET, 0, stream>>>(feat, src, dst, e, s, bufA);
    elu_kernel<<<EB, ET, 0, stream>>>(bufA, N_NODES * 128);

    // ---------------- layer 3 (D=8, head-mean) ----------------
    gemm_kernel<128, 32><<<GB, 128, 0, stream>>>(bufA, W3, feat);
    hipMemsetAsync(m, 0, (size_t)N_NODES * HEADS * 2 * 4, stream);
    hipMemsetAsync(bufA, 0, (size_t)N_NODES * 32 * 4, stream);
    edge_score<8><<<EB, ET, 0, stream>>>(feat, src, dst, attn3, e, m);
    edge_exp<<<EB, ET, 0, stream>>>(e, dst, m, s);
    edge_aggr<8><<<EB, ET, 0, stream>>>(feat, src, dst, e, s, bufA);
    mean_kernel<<<EB, ET, 0, stream>>>(bufA, out);
}

// Round 3
// 636.086 us; speedup vs baseline: 8.1529x; 8.1529x over previous
//
#include <hip/hip_runtime.h>
#include <hip/hip_bf16.h>
#include <math.h>

#define N_NODES 50000
#define N_EDGES 800000
#define HEADS 4
#define NEG 0.2f

// ---------- GEMM: out[N, FOUT] = h[N, FIN] @ W[FIN, FOUT] ----------
template<int FIN, int FOUT>
__global__ __launch_bounds__(128) void gemm_kernel(const float* __restrict__ h,
                                                   const float* __restrict__ W,
                                                   float* __restrict__ out) {
    constexpr int ROWS = 16;
    constexpr int SUBS = 128 / FOUT;   // thread row-subgroups (1 or 4)
    constexpr int RPT  = ROWS / SUBS;  // rows per thread (16 or 4)
    __shared__ float hs[ROWS][FIN];
    const int tid = threadIdx.x;
    const int rbase = blockIdx.x * ROWS;
    for (int i = tid; i < ROWS * FIN; i += 128) {
        int r = i / FIN, c = i % FIN;
        int gr = rbase + r;
        hs[r][c] = (gr < N_NODES) ? h[(size_t)gr * FIN + c] : 0.f;
    }
    __syncthreads();
    const int col = tid % FOUT;
    const int sub = tid / FOUT;
    float acc[RPT];
#pragma unroll
    for (int i = 0; i < RPT; ++i) acc[i] = 0.f;
    for (int k = 0; k < FIN; ++k) {
        float w = W[k * FOUT + col];
#pragma unroll
        for (int i = 0; i < RPT; ++i) acc[i] += hs[sub * RPT + i][k] * w;
    }
#pragma unroll
    for (int i = 0; i < RPT; ++i) {
        int gr = rbase + sub * RPT + i;
        if (gr < N_NODES) out[(size_t)gr * FOUT + col] = acc[i];
    }
}

// ---------- CSR build ----------
__global__ __launch_bounds__(256) void deg_count(const int* __restrict__ dst,
                                                 int* __restrict__ deg) {
    int e = blockIdx.x * blockDim.x + threadIdx.x;
    if (e < N_EDGES) atomicAdd(&deg[dst[e]], 1);
}

// exclusive scan of deg[0..N) -> row_ptr[0..N], single block of 1024
__global__ __launch_bounds__(1024) void scan_kernel(const int* __restrict__ deg,
                                                    int* __restrict__ row_ptr) {
    __shared__ int tile[1024];
    __shared__ int s_carry;
    const int tid = threadIdx.x;
    if (tid == 0) { s_carry = 0; row_ptr[0] = 0; }
    __syncthreads();
    for (int base = 0; base < N_NODES; base += 1024) {
        int i = base + tid;
        tile[tid] = (i < N_NODES) ? deg[i] : 0;
        __syncthreads();
        for (int off = 1; off < 1024; off <<= 1) {
            int t = (tid >= off) ? tile[tid - off] : 0;
            __syncthreads();
            tile[tid] += t;
            __syncthreads();
        }
        int carry = s_carry;
        if (i < N_NODES) row_ptr[i + 1] = carry + tile[tid];
        __syncthreads();
        if (tid == 1023) s_carry = carry + tile[1023];
        __syncthreads();
    }
}

__global__ __launch_bounds__(256) void scatter_kernel(const int* __restrict__ src,
                                                      const int* __restrict__ dst,
                                                      int* __restrict__ woff,
                                                      int* __restrict__ csr_src) {
    int e = blockIdx.x * blockDim.x + threadIdx.x;
    if (e < N_EDGES) {
        int pos = atomicAdd(&woff[dst[e]], 1);
        csr_src[pos] = src[e];
    }
}

// ---------- fused dst-centric GATv2 layer (online softmax, no atomics) ----------
// MODE 0: ELU epilogue, write [N, H*D] row.  MODE 1 (D=8): head-mean, write [N, 8].
template<int D, int MODE>
__global__ __launch_bounds__(256) void fused_gat(const float* __restrict__ feat,
                                                 const int* __restrict__ row_ptr,
                                                 const int* __restrict__ csr_src,
                                                 const float* __restrict__ attn,
                                                 float* __restrict__ out) {
    constexpr int F   = HEADS * D;   // floats per row (128 or 32)
    constexpr int LPN = F / 4;       // lanes per node (32 or 8)
    constexpr int NPW = 64 / LPN;    // nodes per wave (2 or 8)
    const int lane = threadIdx.x & 63;
    const int wave = (blockIdx.x * blockDim.x + threadIdx.x) >> 6;
    const int sub  = lane / LPN;
    const int l    = lane % LPN;
    const int v    = wave * NPW + sub;
    if (v >= N_NODES) return;

    const int head = (l * 4) / D;
    const float4 a4 = *(const float4*)(attn + (l * 4));     // attn[head][dpos..]
    const float4 fv = *(const float4*)(feat + (size_t)v * F + l * 4);

    float m = -INFINITY, s = 0.f;
    float4 acc = {0.f, 0.f, 0.f, 0.f};

    const int beg = row_ptr[v], end = row_ptr[v + 1];
    for (int j = beg; j < end; ++j) {
        const int u = csr_src[j];
        const float4 fu = *(const float4*)(feat + (size_t)u * F + l * 4);
        float t, sc = 0.f;
        t = fu.x + fv.x; t = t > 0.f ? t : t * NEG; sc += t * a4.x;
        t = fu.y + fv.y; t = t > 0.f ? t : t * NEG; sc += t * a4.y;
        t = fu.z + fv.z; t = t > 0.f ? t : t * NEG; sc += t * a4.z;
        t = fu.w + fv.w; t = t > 0.f ? t : t * NEG; sc += t * a4.w;
#pragma unroll
        for (int off = 1; off < D / 4; off <<= 1)
            sc += __shfl_xor(sc, off, 64);
        const float mnew  = fmaxf(m, sc);
        const float scale = expf(m - mnew);   // m=-inf -> 0
        const float p     = expf(sc - mnew);
        s = s * scale + p;
        acc.x = acc.x * scale + fu.x * p;
        acc.y = acc.y * scale + fu.y * p;
        acc.z = acc.z * scale + fu.z * p;
        acc.w = acc.w * scale + fu.w * p;
        m = mnew;
    }

    const float inv = (s > 0.f) ? 1.f / s : 0.f;
    float4 r;
    r.x = acc.x * inv; r.y = acc.y * inv; r.z = acc.z * inv; r.w = acc.w * inv;
    if (MODE == 0) {
        r.x = r.x > 0.f ? r.x : expm1f(r.x);
        r.y = r.y > 0.f ? r.y : expm1f(r.y);
        r.z = r.z > 0.f ? r.z : expm1f(r.z);
        r.w = r.w > 0.f ? r.w : expm1f(r.w);
        *(float4*)(out + (size_t)v * F + l * 4) = r;
    } else {
        // mean over heads: lanes at stride D/4 (=2) within the 8-lane group
        r.x += __shfl_xor(r.x, 2, 64); r.y += __shfl_xor(r.y, 2, 64);
        r.z += __shfl_xor(r.z, 2, 64); r.w += __shfl_xor(r.w, 2, 64);
        r.x += __shfl_xor(r.x, 4, 64); r.y += __shfl_xor(r.y, 4, 64);
        r.z += __shfl_xor(r.z, 4, 64); r.w += __shfl_xor(r.w, 4, 64);
        if (l < 2) {
            r.x *= 0.25f; r.y *= 0.25f; r.z *= 0.25f; r.w *= 0.25f;
            *(float4*)(out + (size_t)v * 8 + l * 4) = r;
        }
    }
    (void)head;
}

extern "C" void kernel_launch(void* const* d_in, const int* in_sizes, int n_in,
                              void* d_out, int out_size, void* d_ws, size_t ws_size,
                              hipStream_t stream) {
    const float* features = (const float*)d_in[0];
    const float* W0 = (const float*)d_in[1];  const float* attn0 = (const float*)d_in[2];
    const float* W1 = (const float*)d_in[3];  const float* attn1 = (const float*)d_in[4];
    const float* W2 = (const float*)d_in[5];  const float* attn2 = (const float*)d_in[6];
    const float* W3 = (const float*)d_in[7];  const float* attn3 = (const float*)d_in[8];
    const int* src = (const int*)d_in[9];
    const int* dst = (const int*)d_in[10];
    float* out = (float*)d_out;

    // workspace layout
    float* bufA   = (float*)d_ws;                      // N*128 f
    float* feat   = bufA + (size_t)N_NODES * 128;      // N*128 f
    int* row_ptr  = (int*)(feat + (size_t)N_NODES * 128); // N+1
    int* woff     = row_ptr + (N_NODES + 1);           // N
    int* deg      = woff + N_NODES;                    // N
    int* csr_src  = deg + N_NODES;                     // E

    const int EBLK = (N_EDGES + 255) / 256;            // 3125
    const int GB   = (N_NODES + 15) / 16;

    // ---- CSR build (graph static across layers) ----
    hipMemsetAsync(deg, 0, (size_t)N_NODES * 4, stream);
    deg_count<<<EBLK, 256, 0, stream>>>(dst, deg);
    scan_kernel<<<1, 1024, 0, stream>>>(deg, row_ptr);
    hipMemcpyAsync(woff, row_ptr, (size_t)N_NODES * 4, hipMemcpyDeviceToDevice, stream);
    scatter_kernel<<<EBLK, 256, 0, stream>>>(src, dst, woff, csr_src);

    // fused-layer grids
    const int FB32 = ((N_NODES + 1) / 2 * 64 + 255) / 256;   // D=32: 2 nodes/wave
    const int FB8  = ((N_NODES + 7) / 8 * 64 + 255) / 256;   // D=8:  8 nodes/wave

    // ---- layer 0 ----
    gemm_kernel<16, 128><<<GB, 128, 0, stream>>>(features, W0, feat);
    fused_gat<32, 0><<<FB32, 256, 0, stream>>>(feat, row_ptr, csr_src, attn0, bufA);
    // ---- layer 1 ----
    gemm_kernel<128, 128><<<GB, 128, 0, stream>>>(bufA, W1, feat);
    fused_gat<32, 0><<<FB32, 256, 0, stream>>>(feat, row_ptr, csr_src, attn1, bufA);
    // ---- layer 2 ----
    gemm_kernel<128, 128><<<GB, 128, 0, stream>>>(bufA, W2, feat);
    fused_gat<32, 0><<<FB32, 256, 0, stream>>>(feat, row_ptr, csr_src, attn2, bufA);
    // ---- layer 3 (head-mean) ----
    gemm_kernel<128, 32><<<GB, 128, 0, stream>>>(bufA, W3, feat);
    fused_gat<8, 1><<<FB8, 256, 0, stream>>>(feat, row_ptr, csr_src, attn3, out);
}